// Round 3
// baseline (186.367 us; speedup 1.0000x reference)
//
#include <hip/hip_runtime.h>
#include <stdint.h>

#define MARGIN 0.2f
#define INF_BITS 0x7F800000u
#define BM 128
#define BN 256
#define BK 64
#define BUF_ELEMS 24576   // A 128*64 + B 256*64 bf16 elems (48KB)

typedef __attribute__((ext_vector_type(8))) short bfrag;     // 8 bf16 (4 VGPRs)
typedef __attribute__((ext_vector_type(4))) float f32x4;

__device__ __forceinline__ unsigned short f32_to_bf16(float f) {
  unsigned u = __float_as_uint(f);
  u += 0x7FFFu + ((u >> 16) & 1u);   // RNE
  return (unsigned short)(u >> 16);
}

// ---------------- Phase 0: norms, d_ap, bf16 conversion, min-init ----------------
__global__ __launch_bounds__(256) void prep_kernel(
    const float* __restrict__ anchor, const float* __restrict__ positive,
    const float* __restrict__ negative,
    unsigned short* __restrict__ a_bf, unsigned short* __restrict__ n_bf,
    float* __restrict__ a2, float* __restrict__ n2, float* __restrict__ dap,
    unsigned* __restrict__ gsh, unsigned* __restrict__ gv, int D) {
  const int wid  = threadIdx.x >> 6;
  const int lane = threadIdx.x & 63;
  const int row  = blockIdx.x * 4 + wid;
  const size_t base = (size_t)row * D;
  const int epl = D >> 6;
  const int k0  = lane * epl;
  float sa2 = 0.f, sdap = 0.f, sn2 = 0.f;

  for (int c = 0; c < epl; c += 8) {
    const float4* ap = (const float4*)(anchor   + base + k0 + c);
    const float4* pp = (const float4*)(positive + base + k0 + c);
    const float4* np = (const float4*)(negative + base + k0 + c);
    float4 a0 = ap[0], a1 = ap[1];
    float4 p0 = pp[0], p1 = pp[1];
    float4 v0 = np[0], v1 = np[1];
    float aa[8] = {a0.x,a0.y,a0.z,a0.w,a1.x,a1.y,a1.z,a1.w};
    float pv[8] = {p0.x,p0.y,p0.z,p0.w,p1.x,p1.y,p1.z,p1.w};
    float nn[8] = {v0.x,v0.y,v0.z,v0.w,v1.x,v1.y,v1.z,v1.w};
    #pragma unroll
    for (int e = 0; e < 8; e++) {
      sa2 += aa[e] * aa[e];
      float dd = aa[e] - pv[e];
      sdap += dd * dd;
      sn2 += nn[e] * nn[e];
    }
    unsigned au[4], nu[4];
    #pragma unroll
    for (int e = 0; e < 4; e++) {
      au[e] = (unsigned)f32_to_bf16(aa[2*e]) | ((unsigned)f32_to_bf16(aa[2*e+1]) << 16);
      nu[e] = (unsigned)f32_to_bf16(nn[2*e]) | ((unsigned)f32_to_bf16(nn[2*e+1]) << 16);
    }
    *(uint4*)(a_bf + base + k0 + c) = make_uint4(au[0], au[1], au[2], au[3]);
    *(uint4*)(n_bf + base + k0 + c) = make_uint4(nu[0], nu[1], nu[2], nu[3]);
  }
  #pragma unroll
  for (int off = 32; off > 0; off >>= 1) {
    sa2  += __shfl_down(sa2,  off);
    sdap += __shfl_down(sdap, off);
    sn2  += __shfl_down(sn2,  off);
  }
  if (lane == 0) {
    a2[row]  = sa2;
    dap[row] = sdap;
    n2[row]  = sn2;
    gsh[row] = INF_BITS;
    gv[row]  = INF_BITS;
  }
}

// ---------------- Phase 1: triple-buffered pipelined MFMA GEMM + fused min ------
// 128(M)x256(N) tile, BK=64, 8 waves (2Mx4N), per-wave 64x64 output.
// Triple buffer: iter t reads buf[t%3], stages tile t+2 -> buf[(t+2)%3] (freed
// one full iteration earlier => no landing-time race by construction).
// Counted vmcnt(6) once per iter (= tile t+2's loads in flight), raw barriers.
// T2 both-sides XOR swizzle (rule #21), T5 setprio around MFMA clusters.
__global__ __launch_bounds__(512, 2) void gemm_min_kernel(
    const unsigned short* __restrict__ a_bf, const unsigned short* __restrict__ n_bf,
    const float* __restrict__ a2, const float* __restrict__ n2,
    const float* __restrict__ dap, const int* __restrict__ ta, const int* __restrict__ tn,
    unsigned* __restrict__ gsh, unsigned* __restrict__ gv,
    int D, int nit) {
  __shared__ unsigned short lds[3 * BUF_ELEMS];   // 144KB
  __shared__ unsigned lds_msh[BM];
  __shared__ unsigned lds_mv[BM];

  const int tid  = threadIdx.x;
  const int lane = tid & 63;
  const int wid  = tid >> 6;          // 0..7
  const int wm   = wid >> 2;          // 0..1 (M half)
  const int wn   = wid & 3;           // 0..3 (N quarter)
  const int lg   = lane >> 4;         // 0..3
  const int lc   = lane & 15;

  // bijective XCD swizzle (nwg % 8 == 0); i-fast within each XCD chunk so each
  // XCD keeps ~4 B-panels (1MB) L2-resident while streaming A.
  const int nwg = gridDim.x;
  const int wg  = ((int)blockIdx.x & 7) * (nwg >> 3) + ((int)blockIdx.x >> 3);
  const int it  = wg % nit;
  const int jt  = wg / nit;
  const int i0  = it * BM;
  const int j0  = jt * BN;

  if (tid < BM) { lds_msh[tid] = INF_BITS; lds_mv[tid] = INF_BITS; }

  // staging geometry: one instr = 512 thr x 16B = 8KB = 64 rows of 128B.
  // linear LDS dest, swizzled global source col (rule #21): phys slot (tid&7)
  // of row srow holds logical slot (tid&7)^(srow&7).
  const int srow = tid >> 3;                        // 0..63
  const int scol = (((tid & 7) ^ (srow & 7)) << 3); // source col (elems)
  const int nt   = D / BK;                          // 8 for D=512

  #define STAGE_A(kt, c, p)                                                     \
    __builtin_amdgcn_global_load_lds(                                           \
        (const __attribute__((address_space(1))) void*)                         \
            (a_bf + (size_t)(i0 + ((p) << 6) + srow) * D + (kt) * BK + scol),   \
        (__attribute__((address_space(3))) void*)                               \
            (&lds[(c) * BUF_ELEMS + ((p) << 12) + (tid << 3)]), 16, 0, 0)
  #define STAGE_B(kt, c, p)                                                     \
    __builtin_amdgcn_global_load_lds(                                           \
        (const __attribute__((address_space(1))) void*)                         \
            (n_bf + (size_t)(j0 + ((p) << 6) + srow) * D + (kt) * BK + scol),   \
        (__attribute__((address_space(3))) void*)                               \
            (&lds[(c) * BUF_ELEMS + 8192 + ((p) << 12) + (tid << 3)]), 16, 0, 0)

  // fragment read addressing (elems): row*64 + slot*8, slot = (kk*4+lg)^(lc&7)
  const int aRow = wm * 64 + lc;    // + m*16
  const int bRow = wn * 64 + lc;    // + n*16
  const int s0   = lg ^ (lc & 7);
  const int s1   = s0 ^ 4;

  f32x4 acc[4][4];
  #pragma unroll
  for (int m = 0; m < 4; m++)
    #pragma unroll
    for (int n = 0; n < 4; n++)
      acc[m][n] = (f32x4){0.f, 0.f, 0.f, 0.f};

  // prologue: stage tiles 0,1 (12 loads); wait tile 0 (drain to 6)
  STAGE_A(0, 0, 0); STAGE_A(0, 0, 1);
  STAGE_B(0, 0, 0); STAGE_B(0, 0, 1); STAGE_B(0, 0, 2); STAGE_B(0, 0, 3);
  STAGE_A(1, 1, 0); STAGE_A(1, 1, 1);
  STAGE_B(1, 1, 0); STAGE_B(1, 1, 1); STAGE_B(1, 1, 2); STAGE_B(1, 1, 3);
  asm volatile("s_waitcnt vmcnt(6)" ::: "memory");
  __builtin_amdgcn_s_barrier();

  for (int t = 0; t < nt; ++t) {
    const int c   = t % 3;
    const int cs  = (t + 2) % 3;
    const bool st = (t + 2 < nt);
    const int kt2 = t + 2;
    const unsigned short* bufA = &lds[c * BUF_ELEMS];
    const unsigned short* bufB = &lds[c * BUF_ELEMS + 8192];

    bfrag aF[2][2], bF[4][2];

    // ---- P0: read A(m0,m1) + B(n0,n1); stage A parts; MFMA q0 ----
    #pragma unroll
    for (int mi = 0; mi < 2; mi++) {
      aF[mi][0] = *(const bfrag*)(bufA + (aRow + mi * 16) * 64 + s0 * 8);
      aF[mi][1] = *(const bfrag*)(bufA + (aRow + mi * 16) * 64 + s1 * 8);
    }
    #pragma unroll
    for (int n = 0; n < 2; n++) {
      bF[n][0] = *(const bfrag*)(bufB + (bRow + n * 16) * 64 + s0 * 8);
      bF[n][1] = *(const bfrag*)(bufB + (bRow + n * 16) * 64 + s1 * 8);
    }
    if (st) { STAGE_A(kt2, cs, 0); STAGE_A(kt2, cs, 1); }
    __builtin_amdgcn_s_barrier();
    __builtin_amdgcn_s_setprio(1);
    #pragma unroll
    for (int mi = 0; mi < 2; mi++)
      #pragma unroll
      for (int n = 0; n < 2; n++)
        #pragma unroll
        for (int kk = 0; kk < 2; kk++)
          acc[mi][n] = __builtin_amdgcn_mfma_f32_16x16x32_bf16(aF[mi][kk], bF[n][kk], acc[mi][n], 0, 0, 0);
    __builtin_amdgcn_s_setprio(0);
    __builtin_amdgcn_s_barrier();

    // ---- P1: read B(n2,n3); stage B parts 0,1; MFMA q1 ----
    #pragma unroll
    for (int n = 2; n < 4; n++) {
      bF[n][0] = *(const bfrag*)(bufB + (bRow + n * 16) * 64 + s0 * 8);
      bF[n][1] = *(const bfrag*)(bufB + (bRow + n * 16) * 64 + s1 * 8);
    }
    if (st) { STAGE_B(kt2, cs, 0); STAGE_B(kt2, cs, 1); }
    __builtin_amdgcn_s_barrier();
    __builtin_amdgcn_s_setprio(1);
    #pragma unroll
    for (int mi = 0; mi < 2; mi++)
      #pragma unroll
      for (int n = 2; n < 4; n++)
        #pragma unroll
        for (int kk = 0; kk < 2; kk++)
          acc[mi][n] = __builtin_amdgcn_mfma_f32_16x16x32_bf16(aF[mi][kk], bF[n][kk], acc[mi][n], 0, 0, 0);
    __builtin_amdgcn_s_setprio(0);
    __builtin_amdgcn_s_barrier();

    // ---- P2: read A(m2,m3) (reuse aF regs); stage B part 2; MFMA q2 ----
    #pragma unroll
    for (int mi = 0; mi < 2; mi++) {
      aF[mi][0] = *(const bfrag*)(bufA + (aRow + (2 + mi) * 16) * 64 + s0 * 8);
      aF[mi][1] = *(const bfrag*)(bufA + (aRow + (2 + mi) * 16) * 64 + s1 * 8);
    }
    if (st) { STAGE_B(kt2, cs, 2); }
    __builtin_amdgcn_s_barrier();
    __builtin_amdgcn_s_setprio(1);
    #pragma unroll
    for (int mi = 0; mi < 2; mi++)
      #pragma unroll
      for (int n = 2; n < 4; n++)
        #pragma unroll
        for (int kk = 0; kk < 2; kk++)
          acc[2 + mi][n] = __builtin_amdgcn_mfma_f32_16x16x32_bf16(aF[mi][kk], bF[n][kk], acc[2 + mi][n], 0, 0, 0);
    __builtin_amdgcn_s_setprio(0);
    __builtin_amdgcn_s_barrier();

    // ---- P3: stage B part 3; MFMA q3; counted vmcnt ----
    if (st) { STAGE_B(kt2, cs, 3); }
    __builtin_amdgcn_s_barrier();
    __builtin_amdgcn_s_setprio(1);
    #pragma unroll
    for (int mi = 0; mi < 2; mi++)
      #pragma unroll
      for (int n = 0; n < 2; n++)
        #pragma unroll
        for (int kk = 0; kk < 2; kk++)
          acc[2 + mi][n] = __builtin_amdgcn_mfma_f32_16x16x32_bf16(aF[mi][kk], bF[n][kk], acc[2 + mi][n], 0, 0, 0);
    __builtin_amdgcn_s_setprio(0);
    if (t < nt - 2) {
      asm volatile("s_waitcnt vmcnt(6)" ::: "memory");   // tile t+1 landed; t+2 in flight
    } else if (t == nt - 2) {
      asm volatile("s_waitcnt vmcnt(0)" ::: "memory");   // last tile landed
    }
    __builtin_amdgcn_s_barrier();
  }

  // ---- fused epilogue: d = a2[i] + n2[j] - 2*dot; masks; row-min ----
  float n2c[4], thrc[4];
  int tnc[4];
  const int jb = j0 + wn * 64;
  #pragma unroll
  for (int n = 0; n < 4; n++) {
    const int j = jb + n * 16 + lc;
    n2c[n]  = n2[j];
    tnc[n]  = tn[j];
    thrc[n] = dap[j] + MARGIN;   // column-indexed d_ap[j], replicating reference
  }
  #pragma unroll
  for (int m = 0; m < 4; m++) {
    #pragma unroll
    for (int r = 0; r < 4; r++) {
      const int il = wm * 64 + m * 16 + lg * 4 + r;   // C row = (lane>>4)*4 + reg
      const int i  = i0 + il;
      const float a2i = a2[i];
      const int   tai = ta[i];
      float mv = __uint_as_float(INF_BITS);
      float ms = mv;
      #pragma unroll
      for (int n = 0; n < 4; n++) {
        float d = a2i + n2c[n] - 2.0f * acc[m][n][r];
        bool valid = (tai != tnc[n]);
        if (valid) {
          mv = fminf(mv, d);
          if (d > thrc[n]) ms = fminf(ms, d);
        }
      }
      #pragma unroll
      for (int off = 1; off <= 8; off <<= 1) {  // min over 16-lane column group
        mv = fminf(mv, __shfl_xor(mv, off));
        ms = fminf(ms, __shfl_xor(ms, off));
      }
      if (lc == 0) {   // positive floats: uint order == float order
        atomicMin(&lds_mv[il],  __float_as_uint(mv));
        atomicMin(&lds_msh[il], __float_as_uint(ms));
      }
    }
  }

  __syncthreads();
  if (tid < BM) {
    atomicMin(&gv[i0 + tid],  lds_mv[tid]);
    atomicMin(&gsh[i0 + tid], lds_msh[tid]);
  }
}

// ---------------- Phase 2: d_an select + mean(relu) ----------------
__global__ __launch_bounds__(256) void finalize_kernel(
    const float* __restrict__ dap, const unsigned* __restrict__ gsh,
    const unsigned* __restrict__ gv, float* __restrict__ out, int n) {
  __shared__ float red[4];
  float s = 0.f;
  for (int i = threadIdx.x; i < n; i += 256) {
    const unsigned u = gsh[i];
    const unsigned b = (u == INF_BITS) ? gv[i] : u;   // fall back to hardest
    const float dan = __uint_as_float(b);
    const float t = dap[i] - dan + MARGIN;
    s += fmaxf(t, 0.f);
  }
  #pragma unroll
  for (int off = 32; off > 0; off >>= 1) s += __shfl_down(s, off);
  if ((threadIdx.x & 63) == 0) red[threadIdx.x >> 6] = s;
  __syncthreads();
  if (threadIdx.x == 0) out[0] = (red[0] + red[1] + red[2] + red[3]) / (float)n;
}

extern "C" void kernel_launch(void* const* d_in, const int* in_sizes, int n_in,
                              void* d_out, int out_size, void* d_ws, size_t ws_size,
                              hipStream_t stream) {
  const float* anchor   = (const float*)d_in[0];
  const float* positive = (const float*)d_in[1];
  const float* negative = (const float*)d_in[2];
  const int*   ta       = (const int*)d_in[3];
  const int*   tn       = (const int*)d_in[4];
  const int N = in_sizes[3];
  const int D = in_sizes[0] / N;

  unsigned short* a_bf = (unsigned short*)d_ws;                 // N*D bf16
  unsigned short* n_bf = a_bf + (size_t)N * D;                  // N*D bf16
  float* a2  = (float*)(n_bf + (size_t)N * D);                  // N f32
  float* n2  = a2 + N;
  float* dap = n2 + N;
  unsigned* gsh = (unsigned*)(dap + N);                         // N u32 (min bits)
  unsigned* gv  = gsh + N;
  const size_t needed = (size_t)N * D * 4 + (size_t)N * 20;
  if (ws_size < needed) return;

  const int nit = N / BM;          // 64
  const int njt = N / BN;          // 32
  const int nwg = nit * njt;       // 2048, % 8 == 0

  prep_kernel<<<N / 4, 256, 0, stream>>>(anchor, positive, negative,
                                         a_bf, n_bf, a2, n2, dap, gsh, gv, D);
  gemm_min_kernel<<<nwg, 512, 0, stream>>>(a_bf, n_bf, a2, n2, dap,
                                           ta, tn, gsh, gv, D, nit);
  finalize_kernel<<<1, 256, 0, stream>>>(dap, gsh, gv, (float*)d_out, N);
}

// Round 4
// 155.660 us; speedup vs baseline: 1.1973x; 1.1973x over previous
//
#include <hip/hip_runtime.h>
#include <stdint.h>

#define MARGIN 0.2f
#define INF_BITS 0x7F800000u
#define BK 64

typedef __attribute__((ext_vector_type(8))) short bfrag;     // 8 bf16 (4 VGPRs)
typedef __attribute__((ext_vector_type(4))) float f32x4;

__device__ __forceinline__ unsigned short f32_to_bf16(float f) {
  unsigned u = __float_as_uint(f);
  u += 0x7FFFu + ((u >> 16) & 1u);   // RNE
  return (unsigned short)(u >> 16);
}

// ---------------- Phase 0: norms, d_ap, bf16 conversion, min-init ----------------
__global__ __launch_bounds__(256) void prep_kernel(
    const float* __restrict__ anchor, const float* __restrict__ positive,
    const float* __restrict__ negative,
    unsigned short* __restrict__ a_bf, unsigned short* __restrict__ n_bf,
    float* __restrict__ a2, float* __restrict__ n2, float* __restrict__ dap,
    unsigned* __restrict__ gsh, unsigned* __restrict__ gv, int D) {
  const int wid  = threadIdx.x >> 6;
  const int lane = threadIdx.x & 63;
  const int row  = blockIdx.x * 4 + wid;
  const size_t base = (size_t)row * D;
  const int epl = D >> 6;
  const int k0  = lane * epl;
  float sa2 = 0.f, sdap = 0.f, sn2 = 0.f;

  for (int c = 0; c < epl; c += 8) {
    const float4* ap = (const float4*)(anchor   + base + k0 + c);
    const float4* pp = (const float4*)(positive + base + k0 + c);
    const float4* np = (const float4*)(negative + base + k0 + c);
    float4 a0 = ap[0], a1 = ap[1];
    float4 p0 = pp[0], p1 = pp[1];
    float4 v0 = np[0], v1 = np[1];
    float aa[8] = {a0.x,a0.y,a0.z,a0.w,a1.x,a1.y,a1.z,a1.w};
    float pv[8] = {p0.x,p0.y,p0.z,p0.w,p1.x,p1.y,p1.z,p1.w};
    float nn[8] = {v0.x,v0.y,v0.z,v0.w,v1.x,v1.y,v1.z,v1.w};
    #pragma unroll
    for (int e = 0; e < 8; e++) {
      sa2 += aa[e] * aa[e];
      float dd = aa[e] - pv[e];
      sdap += dd * dd;
      sn2 += nn[e] * nn[e];
    }
    unsigned au[4], nu[4];
    #pragma unroll
    for (int e = 0; e < 4; e++) {
      au[e] = (unsigned)f32_to_bf16(aa[2*e]) | ((unsigned)f32_to_bf16(aa[2*e+1]) << 16);
      nu[e] = (unsigned)f32_to_bf16(nn[2*e]) | ((unsigned)f32_to_bf16(nn[2*e+1]) << 16);
    }
    *(uint4*)(a_bf + base + k0 + c) = make_uint4(au[0], au[1], au[2], au[3]);
    *(uint4*)(n_bf + base + k0 + c) = make_uint4(nu[0], nu[1], nu[2], nu[3]);
  }
  #pragma unroll
  for (int off = 32; off > 0; off >>= 1) {
    sa2  += __shfl_down(sa2,  off);
    sdap += __shfl_down(sdap, off);
    sn2  += __shfl_down(sn2,  off);
  }
  if (lane == 0) {
    a2[row]  = sa2;
    dap[row] = sdap;
    n2[row]  = sn2;
    gsh[row] = INF_BITS;
    gv[row]  = INF_BITS;
  }
}

// ---------------- Phase 1: 256x256 8-phase dbuf MFMA GEMM + fused min -----------
// m201 template port: 8 waves (2M x 4N), per-wave C = 128x64, BK=64, 2-K-tile
// iteration with 8 phases; vmcnt(6) at ph4/ph8 only (vmcnt(0) in tail iter).
// LDS groups remapped so each 16KB staged group == one quadrant's read set:
//   A group g rows (global-relative): {h*128 + g*64 + r}  (bit6<->bit7 swap)
//   B group g rows: {q*64 + g*32 + r}                      (grouped by bit5)
// T2 both-sides XOR swizzle (16B slots, key = row&7); T5 setprio per phase.
__global__ __launch_bounds__(512, 2) void gemm_min_kernel(
    const unsigned short* __restrict__ a_bf, const unsigned short* __restrict__ n_bf,
    const float* __restrict__ a2, const float* __restrict__ n2,
    const float* __restrict__ dap, const int* __restrict__ ta, const int* __restrict__ tn,
    unsigned* __restrict__ gsh, unsigned* __restrict__ gv, int D, int nit) {
  __shared__ unsigned short lds[65536];   // 128KB: 2 buf x (A 32KB + B 32KB)
  __shared__ unsigned lds_msh[256];
  __shared__ unsigned lds_mv[256];

  const int tid  = threadIdx.x;
  const int lane = tid & 63;
  const int wid  = tid >> 6;          // 0..7
  const int wm   = wid >> 2;          // 0..1
  const int wn   = wid & 3;           // 0..3
  const int lg   = lane >> 4;         // 0..3
  const int lc   = lane & 15;

  const int nwg = gridDim.x;
  const int wg  = ((int)blockIdx.x & 7) * (nwg >> 3) + ((int)blockIdx.x >> 3);
  const int i0  = (wg % nit) * 256;
  const int j0  = (wg / nit) * 256;

  if (tid < 256) { lds_msh[tid] = INF_BITS; lds_mv[tid] = INF_BITS; }

  const int srow = tid >> 3;                        // 0..63
  const int scol = (((tid & 7) ^ (srow & 7)) << 3); // swizzled src col (elems)
  const int s0   = lg ^ (lc & 7);
  const int s1v  = s0 ^ 4;
  const int aRowB = (wm * 64 + lc) * 64;            // + m2*1024 + group base
  const int bRowB = (wn * 32 + lc) * 64;            // + n2*1024 + group base

#define AGRP(b,g) ((b)*32768 + (g)*8192)
#define BGRP(b,g) ((b)*32768 + 16384 + (g)*8192)

#define STAGE_AG(b,g,kt) do {                                                     \
    __builtin_amdgcn_global_load_lds(                                             \
        (const __attribute__((address_space(1))) void*)                           \
            (a_bf + (size_t)(i0 + (g)*64 + srow) * D + (kt)*BK + scol),           \
        (__attribute__((address_space(3))) void*)(&lds[AGRP(b,g) + (tid<<3)]),    \
        16, 0, 0);                                                                \
    __builtin_amdgcn_global_load_lds(                                             \
        (const __attribute__((address_space(1))) void*)                           \
            (a_bf + (size_t)(i0 + 128 + (g)*64 + srow) * D + (kt)*BK + scol),     \
        (__attribute__((address_space(3))) void*)(&lds[AGRP(b,g) + 4096 + (tid<<3)]), \
        16, 0, 0);                                                                \
  } while (0)

#define STAGE_BG(b,g,kt) do {                                                     \
    __builtin_amdgcn_global_load_lds(                                             \
        (const __attribute__((address_space(1))) void*)                           \
            (n_bf + (size_t)(j0 + (srow>>5)*64 + (g)*32 + (srow&31)) * D          \
             + (kt)*BK + scol),                                                   \
        (__attribute__((address_space(3))) void*)(&lds[BGRP(b,g) + (tid<<3)]),    \
        16, 0, 0);                                                                \
    __builtin_amdgcn_global_load_lds(                                             \
        (const __attribute__((address_space(1))) void*)                           \
            (n_bf + (size_t)(j0 + (2 + (srow>>5))*64 + (g)*32 + (srow&31)) * D    \
             + (kt)*BK + scol),                                                   \
        (__attribute__((address_space(3))) void*)(&lds[BGRP(b,g) + 4096 + (tid<<3)]), \
        16, 0, 0);                                                                \
  } while (0)

#define READ_A(b,mh) do { _Pragma("unroll")                                       \
    for (int m2 = 0; m2 < 4; m2++) {                                              \
      aF[m2][0] = *(const bfrag*)&lds[AGRP(b,mh) + aRowB + m2*1024 + s0*8];       \
      aF[m2][1] = *(const bfrag*)&lds[AGRP(b,mh) + aRowB + m2*1024 + s1v*8];      \
    } } while (0)

#define READ_B(b,nh) do { _Pragma("unroll")                                       \
    for (int n2 = 0; n2 < 2; n2++) {                                              \
      bF[n2][0] = *(const bfrag*)&lds[BGRP(b,nh) + bRowB + n2*1024 + s0*8];       \
      bF[n2][1] = *(const bfrag*)&lds[BGRP(b,nh) + bRowB + n2*1024 + s1v*8];      \
    } } while (0)

#define MFMA_Q(mh,nh) do { _Pragma("unroll")                                      \
    for (int m2 = 0; m2 < 4; m2++) { _Pragma("unroll")                            \
      for (int n2 = 0; n2 < 2; n2++) { _Pragma("unroll")                          \
        for (int kk = 0; kk < 2; kk++)                                            \
          acc[(mh)*4+m2][(nh)*2+n2] = __builtin_amdgcn_mfma_f32_16x16x32_bf16(    \
              aF[m2][kk], bF[n2][kk], acc[(mh)*4+m2][(nh)*2+n2], 0, 0, 0);        \
      } } } while (0)

#define BAR __builtin_amdgcn_s_barrier()
#define P1  __builtin_amdgcn_s_setprio(1)
#define P0  __builtin_amdgcn_s_setprio(0)

  bfrag aF[4][2], bF[2][2];
  f32x4 acc[8][4];
  #pragma unroll
  for (int m = 0; m < 8; m++)
    #pragma unroll
    for (int n = 0; n < 4; n++)
      acc[m][n] = (f32x4){0.f, 0.f, 0.f, 0.f};

  const int nt = D / BK;    // 8
  const int nu = nt >> 1;   // 4

  // prologue: tile0 (all 4 groups -> buf0), tile1 (A_g0, B_g1, A_g1 -> buf1)
  STAGE_AG(0,0,0); STAGE_AG(0,1,0); STAGE_BG(0,0,0); STAGE_BG(0,1,0);
  STAGE_AG(1,0,1); STAGE_BG(1,1,1); STAGE_AG(1,1,1);
  asm volatile("s_waitcnt vmcnt(6)" ::: "memory");   // tile0 landed
  BAR;

  for (int u = 0; u < nu; ++u) {
    const int t2 = 2*u + 2, t3 = 2*u + 3;
    const bool sA   = (t2 < nt);
    const bool sB   = (t3 < nt);
    const bool last = (u == nu - 1);

    // ---- ph1: A_g0+B_g0(buf0) reads; stage buf1.B_g0 (tile 2u+1) ----
    READ_A(0,0); READ_B(0,0);
    STAGE_BG(1,0, 2*u+1);
    BAR; P1; MFMA_Q(0,0); P0; BAR;
    // ---- ph2: B_g1 reads; stage buf0.A_g0 (tile 2u+2) ----
    READ_B(0,1);
    if (sA) STAGE_AG(0,0,t2);
    BAR; P1; MFMA_Q(0,1); P0; BAR;
    // ---- ph3: A_g1 reads; stage buf0.B_g1 ----
    READ_A(0,1);
    if (sA) STAGE_BG(0,1,t2);
    BAR; P1; MFMA_Q(1,1); P0; BAR;
    // ---- ph4: B_g0 re-read; stage buf0.A_g1; vmcnt guards buf1 (tile 2u+1) ----
    READ_B(0,0);
    if (sA) STAGE_AG(0,1,t2);
    if (last) { asm volatile("s_waitcnt vmcnt(0)" ::: "memory"); }
    else      { asm volatile("s_waitcnt vmcnt(6)" ::: "memory"); }
    BAR; P1; MFMA_Q(1,0); P0; BAR;
    // ---- ph5: A_g0+B_g0(buf1) reads; stage buf0.B_g0 ----
    READ_A(1,0); READ_B(1,0);
    if (sA) STAGE_BG(0,0,t2);
    BAR; P1; MFMA_Q(0,0); P0; BAR;
    // ---- ph6: B_g1 reads; stage buf1.A_g0 (tile 2u+3) ----
    READ_B(1,1);
    if (sB) STAGE_AG(1,0,t3);
    BAR; P1; MFMA_Q(0,1); P0; BAR;
    // ---- ph7: A_g1 reads; stage buf1.B_g1 ----
    READ_A(1,1);
    if (sB) STAGE_BG(1,1,t3);
    BAR; P1; MFMA_Q(1,1); P0; BAR;
    // ---- ph8: B_g0 re-read; stage buf1.A_g1; vmcnt guards buf0 (tile 2u+2) ----
    READ_B(1,0);
    if (sB) STAGE_AG(1,1,t3);
    if (!last) { asm volatile("s_waitcnt vmcnt(6)" ::: "memory"); }
    BAR; P1; MFMA_Q(1,0); P0; BAR;
  }

  // ---- fused epilogue: d = a2[i] + n2[j] - 2*dot; masks; row-min ----
  float n2c[4], thrc[4];
  int tnc[4];
  #pragma unroll
  for (int nf = 0; nf < 4; nf++) {
    const int j = j0 + wn * 64 + nf * 16 + lc;
    n2c[nf]  = n2[j];
    tnc[nf]  = tn[j];
    thrc[nf] = dap[j] + MARGIN;   // column-indexed d_ap[j], replicating reference
  }
  #pragma unroll
  for (int mf = 0; mf < 8; mf++) {
    #pragma unroll
    for (int r = 0; r < 4; r++) {
      const int il = wm * 128 + mf * 16 + lg * 4 + r;   // C row = (lane>>4)*4 + reg
      const int i  = i0 + il;
      const float a2i = a2[i];
      const int   tai = ta[i];
      float mv = __uint_as_float(INF_BITS);
      float ms = mv;
      #pragma unroll
      for (int nf = 0; nf < 4; nf++) {
        float d = a2i + n2c[nf] - 2.0f * acc[mf][nf][r];
        if (tai != tnc[nf]) {
          mv = fminf(mv, d);
          if (d > thrc[nf]) ms = fminf(ms, d);
        }
      }
      #pragma unroll
      for (int off = 1; off <= 8; off <<= 1) {
        mv = fminf(mv, __shfl_xor(mv, off));
        ms = fminf(ms, __shfl_xor(ms, off));
      }
      if (lc == 0) {
        atomicMin(&lds_mv[il],  __float_as_uint(mv));
        atomicMin(&lds_msh[il], __float_as_uint(ms));
      }
    }
  }

  __syncthreads();
  if (tid < 256) {
    atomicMin(&gv[i0 + tid],  lds_mv[tid]);
    atomicMin(&gsh[i0 + tid], lds_msh[tid]);
  }
}

// ---------------- Phase 2: d_an select + mean(relu) ----------------
__global__ __launch_bounds__(256) void finalize_kernel(
    const float* __restrict__ dap, const unsigned* __restrict__ gsh,
    const unsigned* __restrict__ gv, float* __restrict__ out, int n) {
  __shared__ float red[4];
  float s = 0.f;
  for (int i = threadIdx.x; i < n; i += 256) {
    const unsigned u = gsh[i];
    const unsigned b = (u == INF_BITS) ? gv[i] : u;
    const float dan = __uint_as_float(b);
    const float t = dap[i] - dan + MARGIN;
    s += fmaxf(t, 0.f);
  }
  #pragma unroll
  for (int off = 32; off > 0; off >>= 1) s += __shfl_down(s, off);
  if ((threadIdx.x & 63) == 0) red[threadIdx.x >> 6] = s;
  __syncthreads();
  if (threadIdx.x == 0) out[0] = (red[0] + red[1] + red[2] + red[3]) / (float)n;
}

extern "C" void kernel_launch(void* const* d_in, const int* in_sizes, int n_in,
                              void* d_out, int out_size, void* d_ws, size_t ws_size,
                              hipStream_t stream) {
  const float* anchor   = (const float*)d_in[0];
  const float* positive = (const float*)d_in[1];
  const float* negative = (const float*)d_in[2];
  const int*   ta       = (const int*)d_in[3];
  const int*   tn       = (const int*)d_in[4];
  const int N = in_sizes[3];
  const int D = in_sizes[0] / N;

  unsigned short* a_bf = (unsigned short*)d_ws;
  unsigned short* n_bf = a_bf + (size_t)N * D;
  float* a2  = (float*)(n_bf + (size_t)N * D);
  float* n2  = a2 + N;
  float* dap = n2 + N;
  unsigned* gsh = (unsigned*)(dap + N);
  unsigned* gv  = gsh + N;
  const size_t needed = (size_t)N * D * 4 + (size_t)N * 20;
  if (ws_size < needed) return;

  const int nit = N / 256;          // 32
  const int nwg = nit * nit;        // 1024, % 8 == 0

  prep_kernel<<<N / 4, 256, 0, stream>>>(anchor, positive, negative,
                                         a_bf, n_bf, a2, n2, dap, gsh, gv, D);
  gemm_min_kernel<<<nwg, 512, 0, stream>>>(a_bf, n_bf, a2, n2, dap,
                                           ta, tn, gsh, gv, D, nit);
  finalize_kernel<<<1, 256, 0, stream>>>(dap, gsh, gv, (float*)d_out, N);
}